// Round 11
// baseline (230.019 us; speedup 1.0000x reference)
//
#include <hip/hip_runtime.h>

// Problem constants (from reference)
constexpr int NN = 50000;     // nodes
constexpr int NE = 400000;    // edges
constexpr int NV = 3;         // views
constexpr int DF = 128;       // per-view width
constexpr int F  = 384;       // total feature width (NV*DF)
constexpr int TR = 32;        // node rows per block tile
constexpr int NB = (NN + 255) / 256;  // 196 scan blocks
constexpr int SP = 136;       // sT row stride in ushort (+8 pad, 16B aligned)

typedef short  bf16x8 __attribute__((ext_vector_type(8)));
typedef float  f32x4  __attribute__((ext_vector_type(4)));

// ---------------- bf16 helpers ----------------

__device__ __forceinline__ ushort f2bf(float f) {
  unsigned u = __float_as_uint(f);
  u = (u + 0x7fffu + ((u >> 16) & 1u)) >> 16;   // round-nearest-even
  return (ushort)u;
}

// direct global->LDS DMA, 4B per lane; lds dest = uniform base + lane*4
__device__ __forceinline__ void gload_lds4(const ushort* g, unsigned* ldsbase) {
  __builtin_amdgcn_global_load_lds(
      (const __attribute__((address_space(1))) void*)g,
      (__attribute__((address_space(3))) void*)ldsbase, 4, 0, 0);
}

// ---------------- fused prep 0: W1 pack || W2 pack || deg zero ----------------
// W pack layout: pk[(((v*2+s)*4+kb)*8+cb)*512 + lane*8 + j]
//   = bf16_{hi,lo}( W[v][ kb*32 + (lane>>4)*8 + j ][ cb*16 + (lane&15) ] )

__device__ __forceinline__ void wprep_one(const float* __restrict__ W,
                                          ushort* __restrict__ pk, int idx) {
  int j = idx & 7, lane = (idx >> 3) & 63, cb = (idx >> 9) & 7, kb = (idx >> 12) & 3;
  int vs = idx >> 14;
  int v = vs >> 1, s = vs & 1;
  int d = kb * 32 + (lane >> 4) * 8 + j;
  int c = cb * 16 + (lane & 15);
  float w = W[((size_t)v * DF + d) * DF + c];
  ushort hi = f2bf(w);
  ushort outv = hi;
  if (s) outv = f2bf(w - __uint_as_float((unsigned)hi << 16));
  pk[idx] = outv;
}

constexpr int WB1 = (NV * 2 * 16384) / 256;   // 384 blocks
constexpr int WB2 = (2 * 16384) / 256;        // 128 blocks

__global__ void k_prep0(const float* __restrict__ W1, const float* __restrict__ W2,
                        ushort* __restrict__ w1pk, ushort* __restrict__ w2pk,
                        int* __restrict__ deg) {
  int b = blockIdx.x, t = threadIdx.x;
  if (b < WB1) {
    wprep_one(W1, w1pk, b * 256 + t);
  } else if (b < WB1 + WB2) {
    wprep_one(W2, w2pk, (b - WB1) * 256 + t);
  } else {
    int i = (b - WB1 - WB2) * 256 + t;
    if (i < NN) deg[i] = 0;
  }
}

// ---------------- fused prep 1: h -> bf16 convert || edge count ----------------

__global__ void k_cvtcnt(const float* __restrict__ in, ushort* __restrict__ outb,
                         const int* __restrict__ dst, int* __restrict__ deg) {
  int b = blockIdx.x, t = threadIdx.x;
  if (b < 2048) {
    const int n4 = NN * F / 4;
    const float4* in4 = (const float4*)in;
    for (int k = b * 256 + t; k < n4; k += 2048 * 256) {
      float4 x = in4[k];
      ushort4 u;
      u.x = f2bf(x.x); u.y = f2bf(x.y); u.z = f2bf(x.z); u.w = f2bf(x.w);
      *(ushort4*)(outb + (size_t)k * 4) = u;
    }
  } else {
    for (int e = (b - 2048) * 256 + t; e < NE; e += 1024 * 256)
      atomicAdd(&deg[dst[e]], 1);
  }
}

// ---------------- CSR build (by destination) ----------------

__global__ void k_blocksum(const int* __restrict__ deg, int* __restrict__ bsum) {
  __shared__ int s[4];
  int i = blockIdx.x * 256 + threadIdx.x;
  int v = (i < NN) ? deg[i] : 0;
  for (int o = 32; o > 0; o >>= 1) v += __shfl_down(v, o);  // wave64 reduce
  if ((threadIdx.x & 63) == 0) s[threadIdx.x >> 6] = v;
  __syncthreads();
  if (threadIdx.x == 0) bsum[blockIdx.x] = s[0] + s[1] + s[2] + s[3];
}

// parallel one-block exclusive scan over NB block sums
__global__ void k_scanpar(int* __restrict__ bsum, int* __restrict__ offs_n) {
  __shared__ int s[256];
  int t = threadIdx.x;
  int v = (t < NB) ? bsum[t] : 0;
  s[t] = v;
  __syncthreads();
  for (int o = 1; o < 256; o <<= 1) {
    int add = (t >= o) ? s[t - o] : 0;
    __syncthreads();
    s[t] += add;
    __syncthreads();
  }
  if (t < NB) bsum[t] = s[t] - v;      // exclusive
  if (t == NB - 1) *offs_n = s[t];     // offs[NN] = NE
}

__global__ void k_offsets(const int* __restrict__ deg, const int* __restrict__ bsum,
                          int* __restrict__ offs) {
  __shared__ int s[256];
  int t = threadIdx.x;
  int i = blockIdx.x * 256 + t;
  int v = (i < NN) ? deg[i] : 0;
  s[t] = v;
  __syncthreads();
  for (int o = 1; o < 256; o <<= 1) {     // Hillis-Steele inclusive scan
    int add = (t >= o) ? s[t - o] : 0;
    __syncthreads();
    s[t] += add;
    __syncthreads();
  }
  if (i < NN) offs[i] = bsum[blockIdx.x] + s[t] - v;  // exclusive
}

// scatter uses deg itself as a countdown cursor (deg dead afterwards)
__global__ void k_scatter(const int* __restrict__ src, const int* __restrict__ dst,
                          const int* __restrict__ offs, int* __restrict__ deg,
                          int* __restrict__ csr) {
  int i = blockIdx.x * blockDim.x + threadIdx.x;
  int stride = gridDim.x * blockDim.x;
  for (int e = i; e < NE; e += stride) {
    int d = dst[e];
    int pos = offs[d] + atomicSub(&deg[d], 1) - 1;
    csr[pos] = src[e];
  }
}

// ---------------- Fused aggregate + MFMA-GEMM(+bias+ReLU) layer ----------------
// Phase A (DMA-gather): per wave, 8 contiguous rows -> contiguous CSR segment.
// Edge gathers go global->LDS via global_load_lds (no result VGPRs!), batches
// of 16, double-buffered: issue batch b+1 while accumulating batch b.
// Phase B: 3-term hi/lo bf16 MFMA (~fp32 precision).

template <bool OUT_BF16>
__global__ __launch_bounds__(256, 3)
void k_layer(const ushort* __restrict__ feat,      // bf16 features [NN][F]
             const int* __restrict__ offs, const int* __restrict__ csr,
             const ushort* __restrict__ Wpk, int vmul,
             const float* __restrict__ ball, int bstride,
             void* __restrict__ outp) {
  __shared__ ushort sThi[TR][SP];               // 8.7 KB
  __shared__ ushort sTlo[TR][SP];               // 8.7 KB
  __shared__ unsigned sStage[4][2][16][64];     // 32 KB gather staging
  const int t = threadIdx.x;
  const int v = blockIdx.y;
  const float* __restrict__ bias = ball + (size_t)v * bstride;

  const int wave = t >> 6, lane = t & 63;
  const int lane15 = lane & 15, lgrp = lane >> 4;
  const int row0 = blockIdx.x * TR;
  const int vcol = v * DF + lane * 2;   // element offset within feature row
  const int lane2 = lane * 2;

  // ---- Phase A ----
  const int base = row0 + wave * 8;     // 8 contiguous rows for this wave

  // Prefetch the 9 row offsets with one coalesced load
  int ow = 0;
  {
    int ri = base + lane;
    if (lane <= 8) {
      if (ri > NN) ri = NN;
      ow = offs[ri];
    }
  }
  int so[9];
#pragma unroll
  for (int k = 0; k < 9; ++k) so[k] = __builtin_amdgcn_readlane(ow, k);

  float ax[8], ay[8];
#pragma unroll
  for (int r = 0; r < 8; ++r) { ax[r] = 0.f; ay[r] = 0.f; }

  const int eb = so[0], ee = so[8];

  for (int chunk = eb; chunk < ee; chunk += 64) {   // wave-uniform
    int ce = chunk + lane; if (ce > ee - 1) ce = ee - 1;
    int idx = csr[ce];                               // one coalesced index load
    int nb = ee - chunk; if (nb > 64) nb = 64;
    int nbat = (nb + 15) >> 4;

    // accumulate batch bb (edges [chunk+bb*16, chunk+min((bb+1)*16,nb)) ) from LDS
    auto accum = [&](int bb) {
      int w0 = chunk + bb * 16;
      int w1 = chunk + ((bb + 1) * 16 < nb ? (bb + 1) * 16 : nb);
#pragma unroll
      for (int r = 0; r < 8; ++r) {
        int js = so[r] > w0 ? so[r] : w0;
        int je = so[r + 1] < w1 ? so[r + 1] : w1;
        for (int j = js; j < je; ++j) {
          unsigned u = sStage[wave][bb & 1][j - w0][lane];
          ax[r] += __uint_as_float(u << 16);
          ay[r] += __uint_as_float(u & 0xffff0000u);
        }
      }
    };

    // issue batch 0
    {
      int e1 = nb < 16 ? nb : 16;
      for (int e = 0; e < e1; ++e) {
        int s = __builtin_amdgcn_readlane(idx, e);
        gload_lds4(feat + (size_t)s * F + vcol, &sStage[wave][0][e][0]);
      }
    }
    for (int b = 1; b < nbat; ++b) {
      int e0 = b * 16;
      int e1 = (b + 1) * 16 < nb ? (b + 1) * 16 : nb;
      for (int e = e0; e < e1; ++e) {
        int s = __builtin_amdgcn_readlane(idx, e);
        gload_lds4(feat + (size_t)s * F + vcol, &sStage[wave][b & 1][e - e0][0]);
      }
      if (e1 - e0 == 16) {
        asm volatile("s_waitcnt vmcnt(16)" ::: "memory");
      } else {
        asm volatile("s_waitcnt vmcnt(0)" ::: "memory");
      }
      __builtin_amdgcn_sched_barrier(0);
      accum(b - 1);
    }
    asm volatile("s_waitcnt vmcnt(0)" ::: "memory");
    __builtin_amdgcn_sched_barrier(0);
    accum(nbat - 1);
  }

  // hi/lo split of fp32 aggregates -> bf16 arrays in LDS
#pragma unroll
  for (int r = 0; r < 8; ++r) {
    ushort hx = f2bf(ax[r]);
    ushort lx = f2bf(ax[r] - __uint_as_float((unsigned)hx << 16));
    ushort hy = f2bf(ay[r]);
    ushort ly = f2bf(ay[r] - __uint_as_float((unsigned)hy << 16));
    *(unsigned*)&sThi[wave * 8 + r][lane2] = (unsigned)hx | ((unsigned)hy << 16);
    *(unsigned*)&sTlo[wave * 8 + r][lane2] = (unsigned)lx | ((unsigned)ly << 16);
  }
  __syncthreads();

  // ---- Phase B: MFMA GEMM. Wave w -> col-blocks 2w,2w+1; row-blocks 0,1. ----
  const ushort* pkbase = Wpk + (size_t)(v * vmul) * (2 * 4 * 8 * 512);
  const float bv0 = bias[wave * 32 + lane15];
  const float bv1 = bias[wave * 32 + 16 + lane15];
  f32x4 acc00 = {bv0, bv0, bv0, bv0};
  f32x4 acc01 = {bv1, bv1, bv1, bv1};
  f32x4 acc10 = {bv0, bv0, bv0, bv0};
  f32x4 acc11 = {bv1, bv1, bv1, bv1};

#pragma unroll
  for (int kb = 0; kb < 4; ++kb) {
    const int acol = kb * 32 + lgrp * 8;
    bf16x8 ah0 = *(const bf16x8*)&sThi[lane15][acol];
    bf16x8 ah1 = *(const bf16x8*)&sThi[16 + lane15][acol];
    bf16x8 al0 = *(const bf16x8*)&sTlo[lane15][acol];
    bf16x8 al1 = *(const bf16x8*)&sTlo[16 + lane15][acol];
    bf16x8 bh0 = *(const bf16x8*)(pkbase + ((size_t)((0 * 4 + kb) * 8 + wave * 2 + 0)) * 512 + lane * 8);
    bf16x8 bh1 = *(const bf16x8*)(pkbase + ((size_t)((0 * 4 + kb) * 8 + wave * 2 + 1)) * 512 + lane * 8);
    bf16x8 bl0 = *(const bf16x8*)(pkbase + ((size_t)((1 * 4 + kb) * 8 + wave * 2 + 0)) * 512 + lane * 8);
    bf16x8 bl1 = *(const bf16x8*)(pkbase + ((size_t)((1 * 4 + kb) * 8 + wave * 2 + 1)) * 512 + lane * 8);
    acc00 = __builtin_amdgcn_mfma_f32_16x16x32_bf16(ah0, bh0, acc00, 0, 0, 0);
    acc00 = __builtin_amdgcn_mfma_f32_16x16x32_bf16(al0, bh0, acc00, 0, 0, 0);
    acc00 = __builtin_amdgcn_mfma_f32_16x16x32_bf16(ah0, bl0, acc00, 0, 0, 0);
    acc01 = __builtin_amdgcn_mfma_f32_16x16x32_bf16(ah0, bh1, acc01, 0, 0, 0);
    acc01 = __builtin_amdgcn_mfma_f32_16x16x32_bf16(al0, bh1, acc01, 0, 0, 0);
    acc01 = __builtin_amdgcn_mfma_f32_16x16x32_bf16(ah0, bl1, acc01, 0, 0, 0);
    acc10 = __builtin_amdgcn_mfma_f32_16x16x32_bf16(ah1, bh0, acc10, 0, 0, 0);
    acc10 = __builtin_amdgcn_mfma_f32_16x16x32_bf16(al1, bh0, acc10, 0, 0, 0);
    acc10 = __builtin_amdgcn_mfma_f32_16x16x32_bf16(ah1, bl0, acc10, 0, 0, 0);
    acc11 = __builtin_amdgcn_mfma_f32_16x16x32_bf16(ah1, bh1, acc11, 0, 0, 0);
    acc11 = __builtin_amdgcn_mfma_f32_16x16x32_bf16(al1, bh1, acc11, 0, 0, 0);
    acc11 = __builtin_amdgcn_mfma_f32_16x16x32_bf16(ah1, bl1, acc11, 0, 0, 0);
  }

  // ---- Epilogue: relu + store. C/D: col=lane&15, row=(lane>>4)*4+reg ----
  const int colbase = v * DF + wave * 32 + lane15;
#pragma unroll
  for (int rb = 0; rb < 2; ++rb) {
    f32x4 a0 = rb ? acc10 : acc00;
    f32x4 a1 = rb ? acc11 : acc01;
#pragma unroll
    for (int k = 0; k < 4; ++k) {
      int row = row0 + rb * 16 + lgrp * 4 + k;
      if (row < NN) {
        float x0 = a0[k] > 0.f ? a0[k] : 0.f;
        float x1 = a1[k] > 0.f ? a1[k] : 0.f;
        if (OUT_BF16) {
          ushort* ob = (ushort*)outp;
          ob[(size_t)row * F + colbase]      = f2bf(x0);
          ob[(size_t)row * F + colbase + 16] = f2bf(x1);
        } else {
          float* of = (float*)outp;
          of[(size_t)row * F + colbase]      = x0;
          of[(size_t)row * F + colbase + 16] = x1;
        }
      }
    }
  }
}

// ---------------- launch ----------------

static inline size_t align_up(size_t x, size_t a) { return (x + a - 1) & ~(a - 1); }

extern "C" void kernel_launch(void* const* d_in, const int* in_sizes, int n_in,
                              void* d_out, int out_size, void* d_ws, size_t ws_size,
                              hipStream_t stream) {
  const float* h   = (const float*)d_in[0];
  const int*   src = (const int*)d_in[1];
  const int*   dst = (const int*)d_in[2];
  const float* W1  = (const float*)d_in[3];
  const float* b1  = (const float*)d_in[4];
  const float* W2  = (const float*)d_in[5];
  const float* b2  = (const float*)d_in[6];
  float* out = (float*)d_out;

  // Workspace layout
  char* ws = (char*)d_ws;
  size_t o = 0;
  int* deg  = (int*)(ws + o); o = align_up(o + (size_t)NN * 4, 1024);
  int* offs = (int*)(ws + o); o = align_up(o + (size_t)(NN + 1) * 4, 1024);
  int* bsum = (int*)(ws + o); o = align_up(o + 1024, 1024);
  int* csr  = (int*)(ws + o); o = align_up(o + (size_t)NE * 4, 1024);
  ushort* hb   = (ushort*)(ws + o); o = align_up(o + (size_t)NN * F * 2, 1024);  // bf16 h
  ushort* ybuf = (ushort*)(ws + o); o = align_up(o + (size_t)NN * F * 2, 1024);  // bf16 y
  ushort* w1pk = (ushort*)(ws + o); o = align_up(o + (size_t)NV * 2 * 16384 * 2, 1024);
  ushort* w2pk = (ushort*)(ws + o); o = align_up(o + (size_t)1 * 2 * 16384 * 2, 1024);
  (void)ws_size; (void)n_in; (void)in_sizes; (void)out_size;

  // Prep
  k_prep0<<<WB1 + WB2 + NB, 256, 0, stream>>>(W1, W2, w1pk, w2pk, deg);
  k_cvtcnt<<<3072, 256, 0, stream>>>(h, hb, dst, deg);
  k_blocksum<<<NB, 256, 0, stream>>>(deg, bsum);
  k_scanpar<<<1, 256, 0, stream>>>(bsum, offs + NN);
  k_offsets<<<NB, 256, 0, stream>>>(deg, bsum, offs);
  k_scatter<<<1024, 256, 0, stream>>>(src, dst, offs, deg, csr);

  // Two fused layers
  dim3 grid((NN + TR - 1) / TR, NV);
  k_layer<true ><<<grid, 256, 0, stream>>>(hb,   offs, csr, w1pk, 1, b1, DF, ybuf);
  k_layer<false><<<grid, 256, 0, stream>>>(ybuf, offs, csr, w2pk, 0, b2, 0,  out);
}

// Round 13
// 196.215 us; speedup vs baseline: 1.1723x; 1.1723x over previous
//
#include <hip/hip_runtime.h>

// Problem constants (from reference)
constexpr int NN = 50000;     // nodes
constexpr int NE = 400000;    // edges
constexpr int NV = 3;         // views
constexpr int DF = 128;       // per-view width
constexpr int F  = 384;       // total feature width (NV*DF)
constexpr int TR = 32;        // node rows per block tile
constexpr int NB = (NN + 255) / 256;  // 196 scan blocks
constexpr int SP = 136;       // sT row stride in ushort (+8 pad, 16B aligned)

typedef short  bf16x8 __attribute__((ext_vector_type(8)));
typedef float  f32x4  __attribute__((ext_vector_type(4)));

// ---------------- bf16 helpers ----------------

__device__ __forceinline__ ushort f2bf(float f) {
  unsigned u = __float_as_uint(f);
  u = (u + 0x7fffu + ((u >> 16) & 1u)) >> 16;   // round-nearest-even
  return (ushort)u;
}

// ---------------- fused prep 0: W1 pack || W2 pack || deg zero ----------------
// W pack layout: pk[(((v*2+s)*4+kb)*8+cb)*512 + lane*8 + j]
//   = bf16_{hi,lo}( W[v][ kb*32 + (lane>>4)*8 + j ][ cb*16 + (lane&15) ] )

__device__ __forceinline__ void wprep_one(const float* __restrict__ W,
                                          ushort* __restrict__ pk, int idx) {
  int j = idx & 7, lane = (idx >> 3) & 63, cb = (idx >> 9) & 7, kb = (idx >> 12) & 3;
  int vs = idx >> 14;
  int v = vs >> 1, s = vs & 1;
  int d = kb * 32 + (lane >> 4) * 8 + j;
  int c = cb * 16 + (lane & 15);
  float w = W[((size_t)v * DF + d) * DF + c];
  ushort hi = f2bf(w);
  ushort outv = hi;
  if (s) outv = f2bf(w - __uint_as_float((unsigned)hi << 16));
  pk[idx] = outv;
}

constexpr int WB1 = (NV * 2 * 16384) / 256;   // 384 blocks
constexpr int WB2 = (2 * 16384) / 256;        // 128 blocks

__global__ void k_prep0(const float* __restrict__ W1, const float* __restrict__ W2,
                        ushort* __restrict__ w1pk, ushort* __restrict__ w2pk,
                        int* __restrict__ deg) {
  int b = blockIdx.x, t = threadIdx.x;
  if (b < WB1) {
    wprep_one(W1, w1pk, b * 256 + t);
  } else if (b < WB1 + WB2) {
    wprep_one(W2, w2pk, (b - WB1) * 256 + t);
  } else {
    int i = (b - WB1 - WB2) * 256 + t;
    if (i < NN) deg[i] = 0;
  }
}

// ---------------- fused prep 1: h -> bf16 convert || edge count ----------------

__global__ void k_cvtcnt(const float* __restrict__ in, ushort* __restrict__ outb,
                         const int* __restrict__ dst, int* __restrict__ deg) {
  int b = blockIdx.x, t = threadIdx.x;
  if (b < 2048) {
    const int n4 = NN * F / 4;
    const float4* in4 = (const float4*)in;
    for (int k = b * 256 + t; k < n4; k += 2048 * 256) {
      float4 x = in4[k];
      ushort4 u;
      u.x = f2bf(x.x); u.y = f2bf(x.y); u.z = f2bf(x.z); u.w = f2bf(x.w);
      *(ushort4*)(outb + (size_t)k * 4) = u;
    }
  } else {
    for (int e = (b - 2048) * 256 + t; e < NE; e += 1024 * 256)
      atomicAdd(&deg[dst[e]], 1);
  }
}

// ---------------- CSR build (by destination) ----------------

__global__ void k_blocksum(const int* __restrict__ deg, int* __restrict__ bsum) {
  __shared__ int s[4];
  int i = blockIdx.x * 256 + threadIdx.x;
  int v = (i < NN) ? deg[i] : 0;
  for (int o = 32; o > 0; o >>= 1) v += __shfl_down(v, o);  // wave64 reduce
  if ((threadIdx.x & 63) == 0) s[threadIdx.x >> 6] = v;
  __syncthreads();
  if (threadIdx.x == 0) bsum[blockIdx.x] = s[0] + s[1] + s[2] + s[3];
}

// parallel one-block exclusive scan over NB block sums
__global__ void k_scanpar(int* __restrict__ bsum, int* __restrict__ offs_n) {
  __shared__ int s[256];
  int t = threadIdx.x;
  int v = (t < NB) ? bsum[t] : 0;
  s[t] = v;
  __syncthreads();
  for (int o = 1; o < 256; o <<= 1) {
    int add = (t >= o) ? s[t - o] : 0;
    __syncthreads();
    s[t] += add;
    __syncthreads();
  }
  if (t < NB) bsum[t] = s[t] - v;      // exclusive
  if (t == NB - 1) *offs_n = s[t];     // offs[NN] = NE
}

__global__ void k_offsets(const int* __restrict__ deg, const int* __restrict__ bsum,
                          int* __restrict__ offs) {
  __shared__ int s[256];
  int t = threadIdx.x;
  int i = blockIdx.x * 256 + t;
  int v = (i < NN) ? deg[i] : 0;
  s[t] = v;
  __syncthreads();
  for (int o = 1; o < 256; o <<= 1) {     // Hillis-Steele inclusive scan
    int add = (t >= o) ? s[t - o] : 0;
    __syncthreads();
    s[t] += add;
    __syncthreads();
  }
  if (i < NN) offs[i] = bsum[blockIdx.x] + s[t] - v;  // exclusive
}

// scatter uses deg itself as a countdown cursor (deg dead afterwards)
__global__ void k_scatter(const int* __restrict__ src, const int* __restrict__ dst,
                          const int* __restrict__ offs, int* __restrict__ deg,
                          int* __restrict__ csr) {
  int i = blockIdx.x * blockDim.x + threadIdx.x;
  int stride = gridDim.x * blockDim.x;
  for (int e = i; e < NE; e += stride) {
    int d = dst[e];
    int pos = offs[d] + atomicSub(&deg[d], 1) - 1;
    csr[pos] = src[e];
  }
}

// ---------------- Fused aggregate + MFMA-GEMM(+bias+ReLU) layer ----------------
// Phase A (edge-batched): each wave owns 8 CONTIGUOUS rows; their CSR segment
// is contiguous, so one coalesced 64-wide index load serves ~all 8 rows. Row
// offsets prefetched once (1 load + 9 readlanes). Gathers accumulate into
// per-row register accumulators; cross-row loads pipeline freely.
// Phase B: 3-term hi/lo bf16 MFMA (~fp32 precision).

template <bool OUT_BF16>
__global__ __launch_bounds__(256, 4)
void k_layer(const ushort* __restrict__ feat,      // bf16 features [NN][F]
             const int* __restrict__ offs, const int* __restrict__ csr,
             const ushort* __restrict__ Wpk, int vmul,
             const float* __restrict__ ball, int bstride,
             void* __restrict__ outp) {
  __shared__ ushort sThi[TR][SP];   // 8.7 KB
  __shared__ ushort sTlo[TR][SP];   // 8.7 KB
  const int t = threadIdx.x;
  const int v = blockIdx.y;
  const float* __restrict__ bias = ball + (size_t)v * bstride;

  const int wave = t >> 6, lane = t & 63;
  const int lane15 = lane & 15, lgrp = lane >> 4;
  const int row0 = blockIdx.x * TR;
  const int vcol = v * DF + lane * 2;   // element offset within feature row
  const int lane2 = lane * 2;

  // ---- Phase A ----
  const int base = row0 + wave * 8;     // 8 contiguous rows for this wave

  // Prefetch the 9 row offsets with one coalesced load
  int ow = 0;
  {
    int ri = base + lane;
    if (lane <= 8) {
      if (ri > NN) ri = NN;
      ow = offs[ri];
    }
  }
  int so[9];
#pragma unroll
  for (int k = 0; k < 9; ++k) so[k] = __builtin_amdgcn_readlane(ow, k);

  float ax[8], ay[8];
#pragma unroll
  for (int r = 0; r < 8; ++r) { ax[r] = 0.f; ay[r] = 0.f; }

  const int eb = so[0], ee = so[8];
  for (int chunk = eb; chunk < ee; chunk += 64) {   // wave-uniform
    int ce = chunk + lane; if (ce > ee - 1) ce = ee - 1;
    int idx = csr[ce];                               // one coalesced index load
    int cend = chunk + 64 < ee ? chunk + 64 : ee;
#pragma unroll
    for (int r = 0; r < 8; ++r) {                    // static accumulator index
      int js = so[r] > chunk ? so[r] : chunk;
      int je = so[r + 1] < cend ? so[r + 1] : cend;
      int j  = js - chunk;
      int jn = je - chunk;
      for (; j + 4 <= jn; j += 4) {                  // 4 independent gathers
        int s0 = __builtin_amdgcn_readlane(idx, j);
        int s1 = __builtin_amdgcn_readlane(idx, j + 1);
        int s2 = __builtin_amdgcn_readlane(idx, j + 2);
        int s3 = __builtin_amdgcn_readlane(idx, j + 3);
        unsigned u0 = *(const unsigned*)(feat + (size_t)s0 * F + vcol);
        unsigned u1 = *(const unsigned*)(feat + (size_t)s1 * F + vcol);
        unsigned u2 = *(const unsigned*)(feat + (size_t)s2 * F + vcol);
        unsigned u3 = *(const unsigned*)(feat + (size_t)s3 * F + vcol);
        ax[r] += __uint_as_float(u0 << 16); ay[r] += __uint_as_float(u0 & 0xffff0000u);
        ax[r] += __uint_as_float(u1 << 16); ay[r] += __uint_as_float(u1 & 0xffff0000u);
        ax[r] += __uint_as_float(u2 << 16); ay[r] += __uint_as_float(u2 & 0xffff0000u);
        ax[r] += __uint_as_float(u3 << 16); ay[r] += __uint_as_float(u3 & 0xffff0000u);
      }
      for (; j < jn; ++j) {
        int s0 = __builtin_amdgcn_readlane(idx, j);
        unsigned u0 = *(const unsigned*)(feat + (size_t)s0 * F + vcol);
        ax[r] += __uint_as_float(u0 << 16); ay[r] += __uint_as_float(u0 & 0xffff0000u);
      }
    }
  }

  // hi/lo split of fp32 aggregates -> bf16 arrays in LDS
#pragma unroll
  for (int r = 0; r < 8; ++r) {
    ushort hx = f2bf(ax[r]);
    ushort lx = f2bf(ax[r] - __uint_as_float((unsigned)hx << 16));
    ushort hy = f2bf(ay[r]);
    ushort ly = f2bf(ay[r] - __uint_as_float((unsigned)hy << 16));
    *(unsigned*)&sThi[wave * 8 + r][lane2] = (unsigned)hx | ((unsigned)hy << 16);
    *(unsigned*)&sTlo[wave * 8 + r][lane2] = (unsigned)lx | ((unsigned)ly << 16);
  }
  __syncthreads();

  // ---- Phase B: MFMA GEMM. Wave w -> col-blocks 2w,2w+1; row-blocks 0,1. ----
  const ushort* pkbase = Wpk + (size_t)(v * vmul) * (2 * 4 * 8 * 512);
  const float bv0 = bias[wave * 32 + lane15];
  const float bv1 = bias[wave * 32 + 16 + lane15];
  f32x4 acc00 = {bv0, bv0, bv0, bv0};
  f32x4 acc01 = {bv1, bv1, bv1, bv1};
  f32x4 acc10 = {bv0, bv0, bv0, bv0};
  f32x4 acc11 = {bv1, bv1, bv1, bv1};

#pragma unroll
  for (int kb = 0; kb < 4; ++kb) {
    const int acol = kb * 32 + lgrp * 8;
    bf16x8 ah0 = *(const bf16x8*)&sThi[lane15][acol];
    bf16x8 ah1 = *(const bf16x8*)&sThi[16 + lane15][acol];
    bf16x8 al0 = *(const bf16x8*)&sTlo[lane15][acol];
    bf16x8 al1 = *(const bf16x8*)&sTlo[16 + lane15][acol];
    bf16x8 bh0 = *(const bf16x8*)(pkbase + ((size_t)((0 * 4 + kb) * 8 + wave * 2 + 0)) * 512 + lane * 8);
    bf16x8 bh1 = *(const bf16x8*)(pkbase + ((size_t)((0 * 4 + kb) * 8 + wave * 2 + 1)) * 512 + lane * 8);
    bf16x8 bl0 = *(const bf16x8*)(pkbase + ((size_t)((1 * 4 + kb) * 8 + wave * 2 + 0)) * 512 + lane * 8);
    bf16x8 bl1 = *(const bf16x8*)(pkbase + ((size_t)((1 * 4 + kb) * 8 + wave * 2 + 1)) * 512 + lane * 8);
    acc00 = __builtin_amdgcn_mfma_f32_16x16x32_bf16(ah0, bh0, acc00, 0, 0, 0);
    acc00 = __builtin_amdgcn_mfma_f32_16x16x32_bf16(al0, bh0, acc00, 0, 0, 0);
    acc00 = __builtin_amdgcn_mfma_f32_16x16x32_bf16(ah0, bl0, acc00, 0, 0, 0);
    acc01 = __builtin_amdgcn_mfma_f32_16x16x32_bf16(ah0, bh1, acc01, 0, 0, 0);
    acc01 = __builtin_amdgcn_mfma_f32_16x16x32_bf16(al0, bh1, acc01, 0, 0, 0);
    acc01 = __builtin_amdgcn_mfma_f32_16x16x32_bf16(ah0, bl1, acc01, 0, 0, 0);
    acc10 = __builtin_amdgcn_mfma_f32_16x16x32_bf16(ah1, bh0, acc10, 0, 0, 0);
    acc10 = __builtin_amdgcn_mfma_f32_16x16x32_bf16(al1, bh0, acc10, 0, 0, 0);
    acc10 = __builtin_amdgcn_mfma_f32_16x16x32_bf16(ah1, bl0, acc10, 0, 0, 0);
    acc11 = __builtin_amdgcn_mfma_f32_16x16x32_bf16(ah1, bh1, acc11, 0, 0, 0);
    acc11 = __builtin_amdgcn_mfma_f32_16x16x32_bf16(al1, bh1, acc11, 0, 0, 0);
    acc11 = __builtin_amdgcn_mfma_f32_16x16x32_bf16(ah1, bl1, acc11, 0, 0, 0);
  }

  // ---- Epilogue: relu + store. C/D: col=lane&15, row=(lane>>4)*4+reg ----
  const int colbase = v * DF + wave * 32 + lane15;
#pragma unroll
  for (int rb = 0; rb < 2; ++rb) {
    f32x4 a0 = rb ? acc10 : acc00;
    f32x4 a1 = rb ? acc11 : acc01;
#pragma unroll
    for (int k = 0; k < 4; ++k) {
      int row = row0 + rb * 16 + lgrp * 4 + k;
      if (row < NN) {
        float x0 = a0[k] > 0.f ? a0[k] : 0.f;
        float x1 = a1[k] > 0.f ? a1[k] : 0.f;
        if (OUT_BF16) {
          ushort* ob = (ushort*)outp;
          ob[(size_t)row * F + colbase]      = f2bf(x0);
          ob[(size_t)row * F + colbase + 16] = f2bf(x1);
        } else {
          float* of = (float*)outp;
          of[(size_t)row * F + colbase]      = x0;
          of[(size_t)row * F + colbase + 16] = x1;
        }
      }
    }
  }
}

// ---------------- launch ----------------

static inline size_t align_up(size_t x, size_t a) { return (x + a - 1) & ~(a - 1); }

extern "C" void kernel_launch(void* const* d_in, const int* in_sizes, int n_in,
                              void* d_out, int out_size, void* d_ws, size_t ws_size,
                              hipStream_t stream) {
  const float* h   = (const float*)d_in[0];
  const int*   src = (const int*)d_in[1];
  const int*   dst = (const int*)d_in[2];
  const float* W1  = (const float*)d_in[3];
  const float* b1  = (const float*)d_in[4];
  const float* W2  = (const float*)d_in[5];
  const float* b2  = (const float*)d_in[6];
  float* out = (float*)d_out;

  // Workspace layout
  char* ws = (char*)d_ws;
  size_t o = 0;
  int* deg  = (int*)(ws + o); o = align_up(o + (size_t)NN * 4, 1024);
  int* offs = (int*)(ws + o); o = align_up(o + (size_t)(NN + 1) * 4, 1024);
  int* bsum = (int*)(ws + o); o = align_up(o + 1024, 1024);
  int* csr  = (int*)(ws + o); o = align_up(o + (size_t)NE * 4, 1024);
  ushort* hb   = (ushort*)(ws + o); o = align_up(o + (size_t)NN * F * 2, 1024);  // bf16 h
  ushort* ybuf = (ushort*)(ws + o); o = align_up(o + (size_t)NN * F * 2, 1024);  // bf16 y
  ushort* w1pk = (ushort*)(ws + o); o = align_up(o + (size_t)NV * 2 * 16384 * 2, 1024);
  ushort* w2pk = (ushort*)(ws + o); o = align_up(o + (size_t)1 * 2 * 16384 * 2, 1024);
  (void)ws_size; (void)n_in; (void)in_sizes; (void)out_size;

  // Prep
  k_prep0<<<WB1 + WB2 + NB, 256, 0, stream>>>(W1, W2, w1pk, w2pk, deg);
  k_cvtcnt<<<3072, 256, 0, stream>>>(h, hb, dst, deg);
  k_blocksum<<<NB, 256, 0, stream>>>(deg, bsum);
  k_scanpar<<<1, 256, 0, stream>>>(bsum, offs + NN);
  k_offsets<<<NB, 256, 0, stream>>>(deg, bsum, offs);
  k_scatter<<<1024, 256, 0, stream>>>(src, dst, offs, deg, csr);

  // Two fused layers
  dim3 grid((NN + TR - 1) / TR, NV);
  k_layer<true ><<<grid, 256, 0, stream>>>(hb,   offs, csr, w1pk, 1, b1, DF, ybuf);
  k_layer<false><<<grid, 256, 0, stream>>>(ybuf, offs, csr, w2pk, 0, b2, 0,  out);
}